// Round 4
// baseline (259.554 us; speedup 1.0000x reference)
//
#include <hip/hip_runtime.h>
#include <hip/hip_bf16.h>

#define BB 8
#define NN 200000
#define CC 10
#define NBINS 16384
#define TOPK 1000
#define CANDN 4096
#define PROPN 200

// ---- Static device scratch (no dependence on ws_size) ----
__device__ unsigned int g_hist[BB * NBINS];
__device__ int g_candCount[BB];
__device__ int g_binB1[BB];
__device__ float g_scores[(size_t)BB * NN];
__device__ unsigned long long g_cand[BB * CANDN];
__device__ unsigned int g_topk[BB * TOPK];
__device__ float g_tb_box[BB * TOPK * 7];
__device__ double g_su[BB * TOPK * 4];
__device__ double g_area[BB * TOPK];
__device__ float g_tb_score[BB * TOPK];
__device__ int g_tb_lab[BB * TOPK];
__device__ int g_tb_dir[BB * TOPK];
__device__ unsigned long long g_mask[BB * TOPK * 16];
__device__ int g_outIdx[BB * PROPN];
__device__ int g_validCount[BB];

__device__ __forceinline__ unsigned int f2mono(float f) {
  unsigned int u = __float_as_uint(f);
  return (u & 0x80000000u) ? ~u : (u | 0x80000000u);
}

// Kernel 0: zero histogram + candidate counters (idempotent per call).
__global__ void k_init() {
  const int i = blockIdx.x * 256 + threadIdx.x;
  if (i < BB * NBINS) g_hist[i] = 0u;
  if (i < BB) g_candCount[i] = 0;
}

// Kernel 1: per-box max logit over 10 classes + 14-bit-prefix histogram.
__global__ void k_score(const float* __restrict__ cls) {
  __shared__ unsigned int h[NBINS];
  for (int i = threadIdx.x; i < NBINS; i += blockDim.x) h[i] = 0u;
  __syncthreads();
  const int b = blockIdx.y;
  const int base = blockIdx.x * 8192;
  const float* cp = cls + (size_t)b * NN * CC;
  const int lim = min(base + 8192, NN);
  for (int n = base + threadIdx.x; n < lim; n += blockDim.x) {
    const float2* p2 = (const float2*)(cp + (size_t)n * CC);
    float m = -3.4e38f;
#pragma unroll
    for (int c = 0; c < 5; c++) {
      float2 v = p2[c];
      m = fmaxf(m, fmaxf(v.x, v.y));
    }
    g_scores[(size_t)b * NN + n] = m;
    atomicAdd(&h[f2mono(m) >> 18], 1u);
  }
  __syncthreads();
  unsigned int* hg = g_hist + (size_t)b * NBINS;
  for (int i = threadIdx.x; i < NBINS; i += blockDim.x)
    if (h[i]) atomicAdd(&hg[i], h[i]);
}

// Kernel 2: find threshold bin (scan from top until cumulative >= TOPK).
__global__ void k_pickbin() {
  const int b = blockIdx.x;
  __shared__ unsigned int csum[256];
  const unsigned int* h = g_hist + (size_t)b * NBINS;
  unsigned int s = 0;
  const int c0 = threadIdx.x * 64;
  for (int i = 0; i < 64; i++) s += h[c0 + i];
  csum[threadIdx.x] = s;
  __syncthreads();
  if (threadIdx.x == 0) {
    unsigned int cum = 0; int bin = 0; bool done = false;
    for (int cc = 255; cc >= 0 && !done; cc--) {
      if (cum + csum[cc] >= (unsigned)TOPK) {
        for (int i = 63; i >= 0; i--) {
          unsigned int v = h[cc * 64 + i];
          if (cum + v >= (unsigned)TOPK) { bin = cc * 64 + i; done = true; break; }
          cum += v;
        }
      } else {
        cum += csum[cc];
      }
    }
    g_binB1[b] = bin;
  }
}

// Kernel 3: compact candidates (bin >= B1) with wave-aggregated atomics.
__global__ void k_compact() {
  const int b = blockIdx.y;
  const int n = blockIdx.x * 256 + threadIdx.x;
  const int B1 = g_binB1[b];
  bool want = false; unsigned int mono = 0;
  if (n < NN) {
    mono = f2mono(g_scores[(size_t)b * NN + n]);
    want = (int)(mono >> 18) >= B1;
  }
  unsigned long long bal = __ballot(want);
  const int lane = threadIdx.x & 63;
  if (bal) {
    const int leader = __ffsll((long long)bal) - 1;
    int base = 0;
    if (lane == leader) base = atomicAdd(&g_candCount[b], __popcll(bal));
    base = __shfl(base, leader);
    if (want) {
      int pos = base + (int)__popcll(bal & ((1ull << lane) - 1ull));
      if (pos < CANDN)
        g_cand[(size_t)b * CANDN + pos] =
            ((unsigned long long)(~mono) << 32) | (unsigned int)n;
    }
  }
}

// Kernel 4: per-batch bitonic sort; key = (~mono)<<32 | idx.
// ascending == (score desc, index asc) == lax.top_k order.
__global__ __launch_bounds__(1024) void k_sort() {
  __shared__ unsigned long long s[CANDN];
  const int b = blockIdx.x;
  const int cnt = min(g_candCount[b], CANDN);
  for (int i = threadIdx.x; i < CANDN; i += 1024)
    s[i] = (i < cnt) ? g_cand[(size_t)b * CANDN + i] : ~0ull;
  for (int k = 2; k <= CANDN; k <<= 1) {
    for (int j = k >> 1; j > 0; j >>= 1) {
      __syncthreads();
      for (int t = threadIdx.x; t < CANDN / 2; t += 1024) {
        int i = ((t / j) * 2 * j) + (t % j);
        int ij = i + j;
        unsigned long long a = s[i], c2 = s[ij];
        bool up = ((i & k) == 0);
        if ((a > c2) == up) { s[i] = c2; s[ij] = a; }
      }
    }
  }
  __syncthreads();
  for (int i = threadIdx.x; i < TOPK; i += 1024)
    g_topk[(size_t)b * TOPK + i] = (unsigned int)(s[i] & 0xffffffffu);
}

// Kernel 5: gather boxes; label/dir/score; standup boxes in f64.
__global__ void k_gather(const float* __restrict__ box, const float* __restrict__ cls,
                         const float* __restrict__ dirp) {
  const int b = blockIdx.y;
  const int k = blockIdx.x * 256 + threadIdx.x;
  if (k >= TOPK) return;
  const unsigned int n = g_topk[(size_t)b * TOPK + k];
  const float* bp = box + ((size_t)b * NN + n) * 7;
  float bx[7];
#pragma unroll
  for (int c = 0; c < 7; c++) {
    bx[c] = bp[c];
    g_tb_box[((size_t)b * TOPK + k) * 7 + c] = bx[c];
  }
  const float* cp = cls + ((size_t)b * NN + n) * CC;
  float best = cp[0]; int lab = 0;
#pragma unroll
  for (int c = 1; c < CC; c++) { float v = cp[c]; if (v > best) { best = v; lab = c; } }
  g_tb_score[(size_t)b * TOPK + k] = (float)(1.0 / (1.0 + exp(-(double)best)));
  g_tb_lab[(size_t)b * TOPK + k] = lab;
  const float* dp = dirp + ((size_t)b * NN + n) * 2;
  g_tb_dir[(size_t)b * TOPK + k] = (dp[1] > dp[0]) ? 1 : 0;

  const double cx = bx[0], cy = bx[1], w = bx[3], l = bx[4], ang = bx[6];
  const double c_ = cos(ang), s_ = sin(ang);
  const double hw = 0.5 * w, hl = 0.5 * l;
  double rx0 = (-hw) * c_ - (-hl) * s_ + cx;
  double rx1 = (-hw) * c_ - ( hl) * s_ + cx;
  double rx2 = ( hw) * c_ - ( hl) * s_ + cx;
  double rx3 = ( hw) * c_ - (-hl) * s_ + cx;
  double ry0 = (-hw) * s_ + (-hl) * c_ + cy;
  double ry1 = (-hw) * s_ + ( hl) * c_ + cy;
  double ry2 = ( hw) * s_ + ( hl) * c_ + cy;
  double ry3 = ( hw) * s_ + (-hl) * c_ + cy;
  double x1 = fmin(fmin(rx0, rx1), fmin(rx2, rx3));
  double y1 = fmin(fmin(ry0, ry1), fmin(ry2, ry3));
  double x2 = fmax(fmax(rx0, rx1), fmax(rx2, rx3));
  double y2 = fmax(fmax(ry0, ry1), fmax(ry2, ry3));
  double* sp = g_su + ((size_t)b * TOPK + k) * 4;
  sp[0] = x1; sp[1] = y1; sp[2] = x2; sp[3] = y2;
  g_area[(size_t)b * TOPK + k] = (x2 - x1) * (y2 - y1);
}

// Kernel 6: IoU suppression bitmask (f64).
__global__ void k_nms() {
  const int b = blockIdx.y, i = blockIdx.x;
  const double* sb = g_su + (size_t)b * TOPK * 4;
  const double ix1 = sb[(size_t)i * 4 + 0], iy1 = sb[(size_t)i * 4 + 1];
  const double ix2 = sb[(size_t)i * 4 + 2], iy2 = sb[(size_t)i * 4 + 3];
  const double ai = g_area[(size_t)b * TOPK + i];
  for (int it = 0; it < 4; it++) {
    const int j = it * 256 + threadIdx.x;
    bool pred = false;
    if (j < TOPK && j > i) {
      const double* q = sb + (size_t)j * 4;
      double ltx = fmax(ix1, q[0]), lty = fmax(iy1, q[1]);
      double rbx = fmin(ix2, q[2]), rby = fmin(iy2, q[3]);
      double w = fmax(rbx - ltx, 0.0), h = fmax(rby - lty, 0.0);
      double inter = w * h;
      double iou = inter / (ai + g_area[(size_t)b * TOPK + j] - inter + 1e-8);
      pred = iou > 0.1;
    }
    unsigned long long bal = __ballot(pred);
    if ((threadIdx.x & 63) == 0)
      g_mask[((size_t)b * TOPK + i) * 16 + (unsigned)(j >> 6)] = bal;
  }
}

// Kernel 7: serial greedy suppression scan (1 wave per batch).
__global__ void k_scan() {
  const int b = blockIdx.x;
  const int lane = threadIdx.x;
  unsigned long long remv = 0ull;
  int cnt = 0;
  const unsigned long long* mb = g_mask + (size_t)b * TOPK * 16;
  for (int i = 0; i < TOPK; i++) {
    unsigned long long rw = __shfl(remv, i >> 6);
    bool kept = !((rw >> (i & 63)) & 1ull);
    if (kept) {
      if (lane < 16) remv |= mb[(size_t)i * 16 + lane];
      if (cnt < PROPN && lane == 0) g_outIdx[b * PROPN + cnt] = i;
      cnt++;
    }
  }
  if (lane == 0) g_validCount[b] = cnt;
}

// Kernel 8: write FLOAT32 outputs: boxes | ids | scores (d_out is float*,
// since the reference's outputs are float32 — harness reads one f32 array).
__global__ void k_out(float* __restrict__ out, int seg) {
  const int b = blockIdx.x;
  const int r = threadIdx.x;
  if (r >= PROPN) return;
  const int K = g_validCount[b];
  float* boxo = out + ((size_t)b * PROPN + r) * 7;
  float* ido = out + (size_t)seg * 7 + (size_t)b * PROPN + r;
  float* sco = out + (size_t)seg * 8 + (size_t)b * PROPN + r;
  if (r < K) {
    const int i = g_outIdx[b * PROPN + r];
    const float* bx = g_tb_box + ((size_t)b * TOPK + i) * 7;
#pragma unroll
    for (int c = 0; c < 6; c++) boxo[c] = bx[c];
    const double period = 3.14159265358979323846;
    double ang = (double)bx[6];
    double rot = ang - floor(ang / period) * period;
    double na = rot + period * (double)g_tb_dir[(size_t)b * TOPK + i];
    boxo[6] = (float)na;
    *ido = (float)g_tb_lab[(size_t)b * TOPK + i];
    *sco = g_tb_score[(size_t)b * TOPK + i];
  } else {
#pragma unroll
    for (int c = 0; c < 7; c++) boxo[c] = 0.0f;
    *ido = 0.0f;
    *sco = 0.0f;
  }
}

extern "C" void kernel_launch(void* const* d_in, const int* in_sizes, int n_in,
                              void* d_out, int out_size, void* d_ws, size_t ws_size,
                              hipStream_t stream) {
  (void)d_ws; (void)ws_size;
  // Identify inputs by element count (robust to scalar inclusion / ordering).
  const float* box = nullptr;
  const float* cls = nullptr;
  const float* dirp = nullptr;
  for (int i = 0; i < n_in; i++) {
    long long s = in_sizes[i];
    if (s == (long long)BB * NN * 7) box = (const float*)d_in[i];
    else if (s == (long long)BB * NN * CC) cls = (const float*)d_in[i];
    else if (s == (long long)BB * NN * 2) dirp = (const float*)d_in[i];
  }
  const int seg = out_size / 9;  // = BB*PROPN = 1600 when out_size == 14400

  k_init<<<(BB * NBINS + 255) / 256, 256, 0, stream>>>();
  k_score<<<dim3(25, BB), 256, 0, stream>>>(cls);
  k_pickbin<<<BB, 256, 0, stream>>>();
  k_compact<<<dim3((NN + 255) / 256, BB), 256, 0, stream>>>();
  k_sort<<<BB, 1024, 0, stream>>>();
  k_gather<<<dim3(4, BB), 256, 0, stream>>>(box, cls, dirp);
  k_nms<<<dim3(TOPK, BB), 256, 0, stream>>>();
  k_scan<<<BB, 64, 0, stream>>>();
  k_out<<<BB, 256, 0, stream>>>((float*)d_out, seg);
}

// Round 5
// 207.878 us; speedup vs baseline: 1.2486x; 1.2486x over previous
//
#include <hip/hip_runtime.h>
#include <hip/hip_bf16.h>

#define BB 8
#define NN 200000
#define CC 10
#define NBINS 16384
#define TOPK 1000
#define CANDN 4096
#define PROPN 200

// ---- Static device scratch (no dependence on ws_size) ----
__device__ unsigned int g_hist[BB * NBINS];
__device__ int g_candCount[BB];
__device__ int g_binB1[BB];
__device__ float g_scores[(size_t)BB * NN];
__device__ unsigned long long g_cand[BB * CANDN];
__device__ unsigned int g_topk[BB * TOPK];
__device__ float g_tb_box[BB * TOPK * 7];
__device__ double g_su[BB * TOPK * 4];
__device__ double g_area[BB * TOPK];
__device__ float g_tb_score[BB * TOPK];
__device__ int g_tb_lab[BB * TOPK];
__device__ int g_tb_dir[BB * TOPK];
__device__ unsigned long long g_mask[BB * TOPK * 16];
__device__ int g_outIdx[BB * PROPN];
__device__ int g_validCount[BB];

__device__ __forceinline__ unsigned int f2mono(float f) {
  unsigned int u = __float_as_uint(f);
  return (u & 0x80000000u) ? ~u : (u | 0x80000000u);
}

// Kernel 0: zero histogram + candidate counters (idempotent per call).
__global__ void k_init() {
  const int i = blockIdx.x * 256 + threadIdx.x;
  if (i < BB * NBINS) g_hist[i] = 0u;
  if (i < BB) g_candCount[i] = 0;
}

// Kernel 1: per-box max logit + 14-bit-prefix histogram.
// LDS-staged: coalesced float4 global loads, per-thread max from LDS.
#define SCHUNK 8192
__global__ __launch_bounds__(256) void k_score(const float* __restrict__ cls) {
  __shared__ unsigned int h[NBINS];       // 64 KB
  __shared__ float sb[256 * CC];          // 10 KB staging
  for (int i = threadIdx.x; i < NBINS; i += 256) h[i] = 0u;
  __syncthreads();
  const int b = blockIdx.y;
  const int base = blockIdx.x * SCHUNK;
  const float* cp = cls + ((size_t)b * NN + base) * CC;
  const int nbox = min(SCHUNK, NN - base);
  for (int c0 = 0; c0 < nbox; c0 += 256) {
    const int nb = min(256, nbox - c0);      // 256 or 64 (tail) -> nb*CC % 4 == 0
    const int nf4 = nb * CC / 4;
    const float4* src = (const float4*)(cp + (size_t)c0 * CC);
    for (int i = threadIdx.x; i < nf4; i += 256)
      ((float4*)sb)[i] = src[i];
    __syncthreads();
    if (threadIdx.x < nb) {
      const float* p = sb + threadIdx.x * CC;
      float m = p[0];
#pragma unroll
      for (int c = 1; c < CC; c++) m = fmaxf(m, p[c]);
      g_scores[(size_t)b * NN + base + c0 + threadIdx.x] = m;
      atomicAdd(&h[f2mono(m) >> 18], 1u);
    }
    __syncthreads();
  }
  unsigned int* hg = g_hist + (size_t)b * NBINS;
  for (int i = threadIdx.x; i < NBINS; i += 256)
    if (h[i]) atomicAdd(&hg[i], h[i]);
}

// Kernel 2: find threshold bin (scan from top until cumulative >= TOPK).
__global__ void k_pickbin() {
  const int b = blockIdx.x;
  __shared__ unsigned int csum[256];
  const unsigned int* h = g_hist + (size_t)b * NBINS;
  unsigned int s = 0;
  const int c0 = threadIdx.x * 64;
  for (int i = 0; i < 64; i++) s += h[c0 + i];
  csum[threadIdx.x] = s;
  __syncthreads();
  if (threadIdx.x == 0) {
    unsigned int cum = 0; int bin = 0; bool done = false;
    for (int cc = 255; cc >= 0 && !done; cc--) {
      if (cum + csum[cc] >= (unsigned)TOPK) {
        for (int i = 63; i >= 0; i--) {
          unsigned int v = h[cc * 64 + i];
          if (cum + v >= (unsigned)TOPK) { bin = cc * 64 + i; done = true; break; }
          cum += v;
        }
      } else {
        cum += csum[cc];
      }
    }
    g_binB1[b] = bin;
  }
}

// Kernel 3: compact candidates. Per-block LDS buffer + ONE global atomic
// per block (was: one atomic per wave -> 14k serialized same-line atomics).
__global__ __launch_bounds__(256) void k_compact() {
  __shared__ unsigned long long lbuf[CANDN];   // 32 KB
  __shared__ int lcnt, lbase;
  if (threadIdx.x == 0) lcnt = 0;
  __syncthreads();
  const int b = blockIdx.y;
  const int base = blockIdx.x * SCHUNK;
  const int B1 = g_binB1[b];
  const int lim = min(base + SCHUNK, NN);
  for (int n = base + threadIdx.x; n < lim; n += 256) {
    unsigned int mono = f2mono(g_scores[(size_t)b * NN + n]);
    if ((int)(mono >> 18) >= B1) {
      int p = atomicAdd(&lcnt, 1);
      if (p < CANDN)
        lbuf[p] = ((unsigned long long)(~mono) << 32) | (unsigned int)n;
    }
  }
  __syncthreads();
  if (threadIdx.x == 0) {
    int c = min(lcnt, CANDN);
    lbase = atomicAdd(&g_candCount[b], c);
    lcnt = c;
  }
  __syncthreads();
  const int c = lcnt, gb = lbase;
  for (int i = threadIdx.x; i < c; i += 256) {
    int pos = gb + i;
    if (pos < CANDN) g_cand[(size_t)b * CANDN + pos] = lbuf[i];
  }
}

// Kernel 4: per-batch bitonic sort; key = (~mono)<<32 | idx.
// ascending == (score desc, index asc) == lax.top_k order.
__global__ __launch_bounds__(1024) void k_sort() {
  __shared__ unsigned long long s[CANDN];
  const int b = blockIdx.x;
  const int cnt = min(g_candCount[b], CANDN);
  for (int i = threadIdx.x; i < CANDN; i += 1024)
    s[i] = (i < cnt) ? g_cand[(size_t)b * CANDN + i] : ~0ull;
  for (int k = 2; k <= CANDN; k <<= 1) {
    for (int j = k >> 1; j > 0; j >>= 1) {
      __syncthreads();
      for (int t = threadIdx.x; t < CANDN / 2; t += 1024) {
        int i = ((t / j) * 2 * j) + (t % j);
        int ij = i + j;
        unsigned long long a = s[i], c2 = s[ij];
        bool up = ((i & k) == 0);
        if ((a > c2) == up) { s[i] = c2; s[ij] = a; }
      }
    }
  }
  __syncthreads();
  for (int i = threadIdx.x; i < TOPK; i += 1024)
    g_topk[(size_t)b * TOPK + i] = (unsigned int)(s[i] & 0xffffffffu);
}

// Kernel 5: gather boxes; label/dir/score; standup boxes in f64.
__global__ void k_gather(const float* __restrict__ box, const float* __restrict__ cls,
                         const float* __restrict__ dirp) {
  const int b = blockIdx.y;
  const int k = blockIdx.x * 256 + threadIdx.x;
  if (k >= TOPK) return;
  const unsigned int n = g_topk[(size_t)b * TOPK + k];
  const float* bp = box + ((size_t)b * NN + n) * 7;
  float bx[7];
#pragma unroll
  for (int c = 0; c < 7; c++) {
    bx[c] = bp[c];
    g_tb_box[((size_t)b * TOPK + k) * 7 + c] = bx[c];
  }
  const float* cp = cls + ((size_t)b * NN + n) * CC;
  float best = cp[0]; int lab = 0;
#pragma unroll
  for (int c = 1; c < CC; c++) { float v = cp[c]; if (v > best) { best = v; lab = c; } }
  g_tb_score[(size_t)b * TOPK + k] = (float)(1.0 / (1.0 + exp(-(double)best)));
  g_tb_lab[(size_t)b * TOPK + k] = lab;
  const float* dp = dirp + ((size_t)b * NN + n) * 2;
  g_tb_dir[(size_t)b * TOPK + k] = (dp[1] > dp[0]) ? 1 : 0;

  const double cx = bx[0], cy = bx[1], w = bx[3], l = bx[4], ang = bx[6];
  const double c_ = cos(ang), s_ = sin(ang);
  const double hw = 0.5 * w, hl = 0.5 * l;
  double rx0 = (-hw) * c_ - (-hl) * s_ + cx;
  double rx1 = (-hw) * c_ - ( hl) * s_ + cx;
  double rx2 = ( hw) * c_ - ( hl) * s_ + cx;
  double rx3 = ( hw) * c_ - (-hl) * s_ + cx;
  double ry0 = (-hw) * s_ + (-hl) * c_ + cy;
  double ry1 = (-hw) * s_ + ( hl) * c_ + cy;
  double ry2 = ( hw) * s_ + ( hl) * c_ + cy;
  double ry3 = ( hw) * s_ + (-hl) * c_ + cy;
  double x1 = fmin(fmin(rx0, rx1), fmin(rx2, rx3));
  double y1 = fmin(fmin(ry0, ry1), fmin(ry2, ry3));
  double x2 = fmax(fmax(rx0, rx1), fmax(rx2, rx3));
  double y2 = fmax(fmax(ry0, ry1), fmax(ry2, ry3));
  double* sp = g_su + ((size_t)b * TOPK + k) * 4;
  sp[0] = x1; sp[1] = y1; sp[2] = x2; sp[3] = y2;
  g_area[(size_t)b * TOPK + k] = (x2 - x1) * (y2 - y1);
}

// Kernel 6: IoU suppression bitmask (f64).
__global__ void k_nms() {
  const int b = blockIdx.y, i = blockIdx.x;
  const double* sb = g_su + (size_t)b * TOPK * 4;
  const double ix1 = sb[(size_t)i * 4 + 0], iy1 = sb[(size_t)i * 4 + 1];
  const double ix2 = sb[(size_t)i * 4 + 2], iy2 = sb[(size_t)i * 4 + 3];
  const double ai = g_area[(size_t)b * TOPK + i];
  for (int it = 0; it < 4; it++) {
    const int j = it * 256 + threadIdx.x;
    bool pred = false;
    if (j < TOPK && j > i) {
      const double* q = sb + (size_t)j * 4;
      double ltx = fmax(ix1, q[0]), lty = fmax(iy1, q[1]);
      double rbx = fmin(ix2, q[2]), rby = fmin(iy2, q[3]);
      double w = fmax(rbx - ltx, 0.0), h = fmax(rby - lty, 0.0);
      double inter = w * h;
      double iou = inter / (ai + g_area[(size_t)b * TOPK + j] - inter + 1e-8);
      pred = iou > 0.1;
    }
    unsigned long long bal = __ballot(pred);
    if ((threadIdx.x & 63) == 0)
      g_mask[((size_t)b * TOPK + i) * 16 + (unsigned)(j >> 6)] = bal;
  }
}

// Kernel 7: serial greedy scan; mask chunks double-buffered through LDS
// (waves 1-3 prefetch chunk c+1 while wave 0 scans chunk c).
#define SROWS 128
__global__ __launch_bounds__(256) void k_scan() {
  __shared__ unsigned long long sm[2][SROWS * 16];   // 2 x 16 KB
  const int b = blockIdx.x;
  const int tid = threadIdx.x;
  const unsigned long long* mb = g_mask + (size_t)b * TOPK * 16;
  for (int i = tid; i < SROWS * 16; i += 256) sm[0][i] = mb[i];
  __syncthreads();
  const int NCH = (TOPK + SROWS - 1) / SROWS;
  unsigned long long remv = 0ull;
  int cnt = 0;
  for (int ch = 0; ch < NCH; ch++) {
    if (ch + 1 < NCH && tid >= 64) {
      const int r0 = (ch + 1) * SROWS;
      const int nw = min(SROWS, TOPK - r0) * 16;
      for (int i = tid - 64; i < nw; i += 192)
        sm[(ch + 1) & 1][i] = mb[(size_t)r0 * 16 + i];
    }
    if (tid < 64) {
      const int r0 = ch * SROWS;
      const int nr = min(SROWS, TOPK - r0);
      const unsigned long long* buf = sm[ch & 1];
      for (int r = 0; r < nr; r++) {
        const int i = r0 + r;
        unsigned long long rw = __shfl(remv, i >> 6);
        if (!((rw >> (i & 63)) & 1ull)) {
          if (tid < 16) remv |= buf[r * 16 + tid];
          if (cnt < PROPN && tid == 0) g_outIdx[b * PROPN + cnt] = i;
          cnt++;
        }
      }
    }
    __syncthreads();
  }
  if (tid == 0) g_validCount[b] = cnt;
}

// Kernel 8: write FLOAT32 outputs: boxes | ids | scores.
__global__ void k_out(float* __restrict__ out, int seg) {
  const int b = blockIdx.x;
  const int r = threadIdx.x;
  if (r >= PROPN) return;
  const int K = g_validCount[b];
  float* boxo = out + ((size_t)b * PROPN + r) * 7;
  float* ido = out + (size_t)seg * 7 + (size_t)b * PROPN + r;
  float* sco = out + (size_t)seg * 8 + (size_t)b * PROPN + r;
  if (r < K) {
    const int i = g_outIdx[b * PROPN + r];
    const float* bx = g_tb_box + ((size_t)b * TOPK + i) * 7;
#pragma unroll
    for (int c = 0; c < 6; c++) boxo[c] = bx[c];
    const double period = 3.14159265358979323846;
    double ang = (double)bx[6];
    double rot = ang - floor(ang / period) * period;
    double na = rot + period * (double)g_tb_dir[(size_t)b * TOPK + i];
    boxo[6] = (float)na;
    *ido = (float)g_tb_lab[(size_t)b * TOPK + i];
    *sco = g_tb_score[(size_t)b * TOPK + i];
  } else {
#pragma unroll
    for (int c = 0; c < 7; c++) boxo[c] = 0.0f;
    *ido = 0.0f;
    *sco = 0.0f;
  }
}

extern "C" void kernel_launch(void* const* d_in, const int* in_sizes, int n_in,
                              void* d_out, int out_size, void* d_ws, size_t ws_size,
                              hipStream_t stream) {
  (void)d_ws; (void)ws_size;
  const float* box = nullptr;
  const float* cls = nullptr;
  const float* dirp = nullptr;
  for (int i = 0; i < n_in; i++) {
    long long s = in_sizes[i];
    if (s == (long long)BB * NN * 7) box = (const float*)d_in[i];
    else if (s == (long long)BB * NN * CC) cls = (const float*)d_in[i];
    else if (s == (long long)BB * NN * 2) dirp = (const float*)d_in[i];
  }
  const int seg = out_size / 9;  // = BB*PROPN = 1600

  k_init<<<(BB * NBINS + 255) / 256, 256, 0, stream>>>();
  k_score<<<dim3((NN + SCHUNK - 1) / SCHUNK, BB), 256, 0, stream>>>(cls);
  k_pickbin<<<BB, 256, 0, stream>>>();
  k_compact<<<dim3((NN + SCHUNK - 1) / SCHUNK, BB), 256, 0, stream>>>();
  k_sort<<<BB, 1024, 0, stream>>>();
  k_gather<<<dim3(4, BB), 256, 0, stream>>>(box, cls, dirp);
  k_nms<<<dim3(TOPK, BB), 256, 0, stream>>>();
  k_scan<<<BB, 256, 0, stream>>>();
  k_out<<<BB, 256, 0, stream>>>((float*)d_out, seg);
}

// Round 6
// 153.248 us; speedup vs baseline: 1.6937x; 1.3565x over previous
//
#include <hip/hip_runtime.h>
#include <hip/hip_bf16.h>

#define BB 8
#define NN 200000
#define CC 10
#define NBINS 16384
#define TOPK 1000
#define CANDN 4096
#define PROPN 200

// ---- Static device scratch (no dependence on ws_size) ----
__device__ unsigned int g_hist[BB * NBINS];
__device__ int g_candCount[BB];
__device__ int g_binB1[BB];
__device__ float g_scores[(size_t)BB * NN];
__device__ unsigned long long g_cand[BB * CANDN];
__device__ unsigned int g_topk[BB * TOPK];
__device__ float g_tb_box[BB * TOPK * 7];
__device__ double g_su[BB * TOPK * 4];
__device__ double g_area[BB * TOPK];
__device__ float g_tb_score[BB * TOPK];
__device__ int g_tb_lab[BB * TOPK];
__device__ int g_tb_dir[BB * TOPK];
__device__ unsigned long long g_mask[BB * TOPK * 16];
__device__ int g_outIdx[BB * PROPN];
__device__ int g_validCount[BB];

__device__ __forceinline__ unsigned int f2mono(float f) {
  unsigned int u = __float_as_uint(f);
  return (u & 0x80000000u) ? ~u : (u | 0x80000000u);
}

// Kernel 0: zero histogram + candidate counters (idempotent per call).
__global__ void k_init() {
  const int i = blockIdx.x * 256 + threadIdx.x;
  if (i < BB * NBINS) g_hist[i] = 0u;
  if (i < BB) g_candCount[i] = 0;
}

// Kernel 1: per-box max logit + 14-bit-prefix histogram.
// LDS-staged: coalesced float4 global loads, per-thread max from LDS.
#define SCHUNK 8192
__global__ __launch_bounds__(256) void k_score(const float* __restrict__ cls) {
  __shared__ unsigned int h[NBINS];       // 64 KB
  __shared__ float sb[256 * CC];          // 10 KB staging
  for (int i = threadIdx.x; i < NBINS; i += 256) h[i] = 0u;
  __syncthreads();
  const int b = blockIdx.y;
  const int base = blockIdx.x * SCHUNK;
  const float* cp = cls + ((size_t)b * NN + base) * CC;
  const int nbox = min(SCHUNK, NN - base);
  for (int c0 = 0; c0 < nbox; c0 += 256) {
    const int nb = min(256, nbox - c0);      // 256 or 64 (tail) -> nb*CC % 4 == 0
    const int nf4 = nb * CC / 4;
    const float4* src = (const float4*)(cp + (size_t)c0 * CC);
    for (int i = threadIdx.x; i < nf4; i += 256)
      ((float4*)sb)[i] = src[i];
    __syncthreads();
    if (threadIdx.x < nb) {
      const float* p = sb + threadIdx.x * CC;
      float m = p[0];
#pragma unroll
      for (int c = 1; c < CC; c++) m = fmaxf(m, p[c]);
      g_scores[(size_t)b * NN + base + c0 + threadIdx.x] = m;
      atomicAdd(&h[f2mono(m) >> 18], 1u);
    }
    __syncthreads();
  }
  unsigned int* hg = g_hist + (size_t)b * NBINS;
  for (int i = threadIdx.x; i < NBINS; i += 256)
    if (h[i]) atomicAdd(&hg[i], h[i]);
}

// Kernel 2: find threshold bin (scan from top until cumulative >= TOPK).
__global__ void k_pickbin() {
  const int b = blockIdx.x;
  __shared__ unsigned int csum[256];
  const unsigned int* h = g_hist + (size_t)b * NBINS;
  unsigned int s = 0;
  const int c0 = threadIdx.x * 64;
  for (int i = 0; i < 64; i++) s += h[c0 + i];
  csum[threadIdx.x] = s;
  __syncthreads();
  if (threadIdx.x == 0) {
    unsigned int cum = 0; int bin = 0; bool done = false;
    for (int cc = 255; cc >= 0 && !done; cc--) {
      if (cum + csum[cc] >= (unsigned)TOPK) {
        for (int i = 63; i >= 0; i--) {
          unsigned int v = h[cc * 64 + i];
          if (cum + v >= (unsigned)TOPK) { bin = cc * 64 + i; done = true; break; }
          cum += v;
        }
      } else {
        cum += csum[cc];
      }
    }
    g_binB1[b] = bin;
  }
}

// Kernel 3: compact candidates. Per-block LDS buffer + ONE global atomic/block.
__global__ __launch_bounds__(256) void k_compact() {
  __shared__ unsigned long long lbuf[CANDN];   // 32 KB
  __shared__ int lcnt, lbase;
  if (threadIdx.x == 0) lcnt = 0;
  __syncthreads();
  const int b = blockIdx.y;
  const int base = blockIdx.x * SCHUNK;
  const int B1 = g_binB1[b];
  const int lim = min(base + SCHUNK, NN);
  for (int n = base + threadIdx.x; n < lim; n += 256) {
    unsigned int mono = f2mono(g_scores[(size_t)b * NN + n]);
    if ((int)(mono >> 18) >= B1) {
      int p = atomicAdd(&lcnt, 1);
      if (p < CANDN)
        lbuf[p] = ((unsigned long long)(~mono) << 32) | (unsigned int)n;
    }
  }
  __syncthreads();
  if (threadIdx.x == 0) {
    int c = min(lcnt, CANDN);
    lbase = atomicAdd(&g_candCount[b], c);
    lcnt = c;
  }
  __syncthreads();
  const int c = lcnt, gb = lbase;
  for (int i = threadIdx.x; i < c; i += 256) {
    int pos = gb + i;
    if (pos < CANDN) g_cand[(size_t)b * CANDN + pos] = lbuf[i];
  }
}

// Kernel 4: per-batch bitonic sort; key = (~mono)<<32 | idx.
// ascending == (score desc, index asc) == lax.top_k order.
__global__ __launch_bounds__(1024) void k_sort() {
  __shared__ unsigned long long s[CANDN];
  const int b = blockIdx.x;
  const int cnt = min(g_candCount[b], CANDN);
  for (int i = threadIdx.x; i < CANDN; i += 1024)
    s[i] = (i < cnt) ? g_cand[(size_t)b * CANDN + i] : ~0ull;
  for (int k = 2; k <= CANDN; k <<= 1) {
    for (int j = k >> 1; j > 0; j >>= 1) {
      __syncthreads();
      for (int t = threadIdx.x; t < CANDN / 2; t += 1024) {
        int i = ((t / j) * 2 * j) + (t % j);
        int ij = i + j;
        unsigned long long a = s[i], c2 = s[ij];
        bool up = ((i & k) == 0);
        if ((a > c2) == up) { s[i] = c2; s[ij] = a; }
      }
    }
  }
  __syncthreads();
  for (int i = threadIdx.x; i < TOPK; i += 1024)
    g_topk[(size_t)b * TOPK + i] = (unsigned int)(s[i] & 0xffffffffu);
}

// Kernel 5: gather boxes; label/dir/score; standup boxes in f64.
__global__ void k_gather(const float* __restrict__ box, const float* __restrict__ cls,
                         const float* __restrict__ dirp) {
  const int b = blockIdx.y;
  const int k = blockIdx.x * 256 + threadIdx.x;
  if (k >= TOPK) return;
  const unsigned int n = g_topk[(size_t)b * TOPK + k];
  const float* bp = box + ((size_t)b * NN + n) * 7;
  float bx[7];
#pragma unroll
  for (int c = 0; c < 7; c++) {
    bx[c] = bp[c];
    g_tb_box[((size_t)b * TOPK + k) * 7 + c] = bx[c];
  }
  const float* cp = cls + ((size_t)b * NN + n) * CC;
  float best = cp[0]; int lab = 0;
#pragma unroll
  for (int c = 1; c < CC; c++) { float v = cp[c]; if (v > best) { best = v; lab = c; } }
  g_tb_score[(size_t)b * TOPK + k] = (float)(1.0 / (1.0 + exp(-(double)best)));
  g_tb_lab[(size_t)b * TOPK + k] = lab;
  const float* dp = dirp + ((size_t)b * NN + n) * 2;
  g_tb_dir[(size_t)b * TOPK + k] = (dp[1] > dp[0]) ? 1 : 0;

  const double cx = bx[0], cy = bx[1], w = bx[3], l = bx[4], ang = bx[6];
  const double c_ = cos(ang), s_ = sin(ang);
  const double hw = 0.5 * w, hl = 0.5 * l;
  double rx0 = (-hw) * c_ - (-hl) * s_ + cx;
  double rx1 = (-hw) * c_ - ( hl) * s_ + cx;
  double rx2 = ( hw) * c_ - ( hl) * s_ + cx;
  double rx3 = ( hw) * c_ - (-hl) * s_ + cx;
  double ry0 = (-hw) * s_ + (-hl) * c_ + cy;
  double ry1 = (-hw) * s_ + ( hl) * c_ + cy;
  double ry2 = ( hw) * s_ + ( hl) * c_ + cy;
  double ry3 = ( hw) * s_ + (-hl) * c_ + cy;
  double x1 = fmin(fmin(rx0, rx1), fmin(rx2, rx3));
  double y1 = fmin(fmin(ry0, ry1), fmin(ry2, ry3));
  double x2 = fmax(fmax(rx0, rx1), fmax(rx2, rx3));
  double y2 = fmax(fmax(ry0, ry1), fmax(ry2, ry3));
  double* sp = g_su + ((size_t)b * TOPK + k) * 4;
  sp[0] = x1; sp[1] = y1; sp[2] = x2; sp[3] = y2;
  g_area[(size_t)b * TOPK + k] = (x2 - x1) * (y2 - y1);
}

// Kernel 6: IoU suppression bitmask (f64).
__global__ void k_nms() {
  const int b = blockIdx.y, i = blockIdx.x;
  const double* sb = g_su + (size_t)b * TOPK * 4;
  const double ix1 = sb[(size_t)i * 4 + 0], iy1 = sb[(size_t)i * 4 + 1];
  const double ix2 = sb[(size_t)i * 4 + 2], iy2 = sb[(size_t)i * 4 + 3];
  const double ai = g_area[(size_t)b * TOPK + i];
  for (int it = 0; it < 4; it++) {
    const int j = it * 256 + threadIdx.x;
    bool pred = false;
    if (j < TOPK && j > i) {
      const double* q = sb + (size_t)j * 4;
      double ltx = fmax(ix1, q[0]), lty = fmax(iy1, q[1]);
      double rbx = fmin(ix2, q[2]), rby = fmin(iy2, q[3]);
      double w = fmax(rbx - ltx, 0.0), h = fmax(rby - lty, 0.0);
      double inter = w * h;
      double iou = inter / (ai + g_area[(size_t)b * TOPK + j] - inter + 1e-8);
      pred = iou > 0.1;
    }
    unsigned long long bal = __ballot(pred);
    if ((threadIdx.x & 63) == 0)
      g_mask[((size_t)b * TOPK + i) * 16 + (unsigned)(j >> 6)] = bal;
  }
}

// Kernel 7: greedy suppression scan, kept-row-proportional.
// One wave per batch. Lane j<16 accumulates suppression word j (remv).
// Per 64-row group: cur = group word; ffsll jumps to next KEPT row only;
// suppressed rows cost zero iterations. Early-exit at PROPN kept.
__global__ __launch_bounds__(64) void k_scan() {
  const int b = blockIdx.x;
  const int lane = threadIdx.x;
  const unsigned long long* mb = g_mask + (size_t)b * TOPK * 16;
  unsigned long long remv = 0ull;   // lane j<16: accumulated mask word j
  int cnt = 0;
  for (int g = 0; g < 16 && cnt < PROPN; g++) {
    unsigned long long cur = __shfl(remv, g);
    const int rmax = min(64, TOPK - g * 64);   // last group: 1000-960=40 rows
    const unsigned long long vmask =
        (rmax >= 64) ? ~0ull : ((1ull << rmax) - 1ull);
    unsigned long long todo = ~cur & vmask;
    while (todo) {
      const int r = __ffsll((long long)todo) - 1;
      const int i = g * 64 + r;
      if (cnt < PROPN && lane == 0) g_outIdx[b * PROPN + cnt] = i;
      cnt++;
      if (cnt >= PROPN) break;   // rows beyond 200th kept can't affect output
      // lane-parallel load of mask row i (16 x u64 = 128B, L2-resident)
      unsigned long long mw = (lane < 16) ? mb[(size_t)i * 16 + lane] : 0ull;
      remv |= mw;
      cur |= __shfl(mw, g);      // row i's word for this group
      const unsigned long long above = (r >= 63) ? 0ull : (~0ull << (r + 1));
      todo = ~cur & vmask & above;
    }
  }
  if (lane == 0) g_validCount[b] = cnt;
}

// Kernel 8: write FLOAT32 outputs: boxes | ids | scores.
__global__ void k_out(float* __restrict__ out, int seg) {
  const int b = blockIdx.x;
  const int r = threadIdx.x;
  if (r >= PROPN) return;
  const int K = g_validCount[b];
  float* boxo = out + ((size_t)b * PROPN + r) * 7;
  float* ido = out + (size_t)seg * 7 + (size_t)b * PROPN + r;
  float* sco = out + (size_t)seg * 8 + (size_t)b * PROPN + r;
  if (r < K) {
    const int i = g_outIdx[b * PROPN + r];
    const float* bx = g_tb_box + ((size_t)b * TOPK + i) * 7;
#pragma unroll
    for (int c = 0; c < 6; c++) boxo[c] = bx[c];
    const double period = 3.14159265358979323846;
    double ang = (double)bx[6];
    double rot = ang - floor(ang / period) * period;
    double na = rot + period * (double)g_tb_dir[(size_t)b * TOPK + i];
    boxo[6] = (float)na;
    *ido = (float)g_tb_lab[(size_t)b * TOPK + i];
    *sco = g_tb_score[(size_t)b * TOPK + i];
  } else {
#pragma unroll
    for (int c = 0; c < 7; c++) boxo[c] = 0.0f;
    *ido = 0.0f;
    *sco = 0.0f;
  }
}

extern "C" void kernel_launch(void* const* d_in, const int* in_sizes, int n_in,
                              void* d_out, int out_size, void* d_ws, size_t ws_size,
                              hipStream_t stream) {
  (void)d_ws; (void)ws_size;
  const float* box = nullptr;
  const float* cls = nullptr;
  const float* dirp = nullptr;
  for (int i = 0; i < n_in; i++) {
    long long s = in_sizes[i];
    if (s == (long long)BB * NN * 7) box = (const float*)d_in[i];
    else if (s == (long long)BB * NN * CC) cls = (const float*)d_in[i];
    else if (s == (long long)BB * NN * 2) dirp = (const float*)d_in[i];
  }
  const int seg = out_size / 9;  // = BB*PROPN = 1600

  k_init<<<(BB * NBINS + 255) / 256, 256, 0, stream>>>();
  k_score<<<dim3((NN + SCHUNK - 1) / SCHUNK, BB), 256, 0, stream>>>(cls);
  k_pickbin<<<BB, 256, 0, stream>>>();
  k_compact<<<dim3((NN + SCHUNK - 1) / SCHUNK, BB), 256, 0, stream>>>();
  k_sort<<<BB, 1024, 0, stream>>>();
  k_gather<<<dim3(4, BB), 256, 0, stream>>>(box, cls, dirp);
  k_nms<<<dim3(TOPK, BB), 256, 0, stream>>>();
  k_scan<<<BB, 64, 0, stream>>>();
  k_out<<<BB, 256, 0, stream>>>((float*)d_out, seg);
}

// Round 7
// 128.017 us; speedup vs baseline: 2.0275x; 1.1971x over previous
//
#include <hip/hip_runtime.h>
#include <hip/hip_bf16.h>

#define BB 8
#define NN 200000
#define CC 10
#define NBINS 16384
#define TOPK 1000
#define CANDN 4096
#define PROPN 200

// ---- Static device scratch (no dependence on ws_size) ----
__device__ unsigned int g_hist[BB * NBINS];
__device__ int g_candCount[BB];
__device__ int g_binB1[BB];
__device__ float g_scores[(size_t)BB * NN];
__device__ unsigned long long g_cand[BB * CANDN];
__device__ unsigned int g_topk[BB * TOPK];
__device__ float g_tb_box[BB * TOPK * 7];
__device__ double g_su[BB * TOPK * 4];
__device__ double g_area[BB * TOPK];
__device__ float g_tb_score[BB * TOPK];
__device__ int g_tb_lab[BB * TOPK];
__device__ int g_tb_dir[BB * TOPK];
__device__ unsigned long long g_mask[BB * TOPK * 16];
__device__ int g_outIdx[BB * PROPN];
__device__ int g_validCount[BB];

__device__ __forceinline__ unsigned int f2mono(float f) {
  unsigned int u = __float_as_uint(f);
  return (u & 0x80000000u) ? ~u : (u | 0x80000000u);
}

// Kernel 0: zero histogram + candidate counters (idempotent per call).
__global__ void k_init() {
  const int i = blockIdx.x * 256 + threadIdx.x;
  if (i < BB * NBINS) g_hist[i] = 0u;
  if (i < BB) g_candCount[i] = 0;
}

// Kernel 1: PURE STREAMING per-box max logit (no histogram, 10KB LDS only
// -> high occupancy; histogram moved to k_hist on the L2-hot scores array).
#define SCHUNK 2048
__global__ __launch_bounds__(256) void k_score(const float* __restrict__ cls) {
  __shared__ float sb[256 * CC];          // 10 KB staging
  const int b = blockIdx.y;
  const int base = blockIdx.x * SCHUNK;
  const float* cp = cls + ((size_t)b * NN + base) * CC;
  const int nbox = min(SCHUNK, NN - base);
  for (int c0 = 0; c0 < nbox; c0 += 256) {
    const int nb = min(256, nbox - c0);      // 256 or 64 (tail): nb*CC % 4 == 0
    const int nf4 = nb * CC / 4;
    const float4* src = (const float4*)(cp + (size_t)c0 * CC);
    for (int i = threadIdx.x; i < nf4; i += 256)
      ((float4*)sb)[i] = src[i];
    __syncthreads();
    if (threadIdx.x < nb) {
      const float2* p = (const float2*)(sb + threadIdx.x * CC);  // 8B-aligned
      float2 v0 = p[0], v1 = p[1], v2 = p[2], v3 = p[3], v4 = p[4];
      float m = fmaxf(fmaxf(fmaxf(v0.x, v0.y), fmaxf(v1.x, v1.y)),
                      fmaxf(fmaxf(v2.x, v2.y),
                            fmaxf(fmaxf(v3.x, v3.y), fmaxf(v4.x, v4.y))));
      g_scores[(size_t)b * NN + base + c0 + threadIdx.x] = m;
    }
    __syncthreads();
  }
}

// Kernel 1b: 14-bit-prefix histogram from g_scores (L2/L3-hot, 6.4 MB).
#define HCHUNK 4096
__global__ __launch_bounds__(256) void k_hist() {
  __shared__ unsigned int h[NBINS];       // 64 KB
  for (int i = threadIdx.x; i < NBINS; i += 256) h[i] = 0u;
  __syncthreads();
  const int b = blockIdx.y;
  const int base = blockIdx.x * HCHUNK;
  const int nv = min(HCHUNK, NN - base) / 4;   // all multiples of 4
  const float4* sp = (const float4*)(g_scores + (size_t)b * NN + base);
  for (int i = threadIdx.x; i < nv; i += 256) {
    float4 v = sp[i];
    atomicAdd(&h[f2mono(v.x) >> 18], 1u);
    atomicAdd(&h[f2mono(v.y) >> 18], 1u);
    atomicAdd(&h[f2mono(v.z) >> 18], 1u);
    atomicAdd(&h[f2mono(v.w) >> 18], 1u);
  }
  __syncthreads();
  unsigned int* hg = g_hist + (size_t)b * NBINS;
  for (int i = threadIdx.x; i < NBINS; i += 256)
    if (h[i]) atomicAdd(&hg[i], h[i]);
}

// Kernel 2: find threshold bin (scan from top until cumulative >= TOPK).
__global__ void k_pickbin() {
  const int b = blockIdx.x;
  __shared__ unsigned int csum[256];
  const unsigned int* h = g_hist + (size_t)b * NBINS;
  unsigned int s = 0;
  const int c0 = threadIdx.x * 64;
  for (int i = 0; i < 64; i++) s += h[c0 + i];
  csum[threadIdx.x] = s;
  __syncthreads();
  if (threadIdx.x == 0) {
    unsigned int cum = 0; int bin = 0; bool done = false;
    for (int cc = 255; cc >= 0 && !done; cc--) {
      if (cum + csum[cc] >= (unsigned)TOPK) {
        for (int i = 63; i >= 0; i--) {
          unsigned int v = h[cc * 64 + i];
          if (cum + v >= (unsigned)TOPK) { bin = cc * 64 + i; done = true; break; }
          cum += v;
        }
      } else {
        cum += csum[cc];
      }
    }
    g_binB1[b] = bin;
  }
}

// Kernel 3: compact candidates. Per-block LDS buffer + ONE global atomic/block.
__global__ __launch_bounds__(256) void k_compact() {
  __shared__ unsigned long long lbuf[CANDN];   // 32 KB
  __shared__ int lcnt, lbase;
  if (threadIdx.x == 0) lcnt = 0;
  __syncthreads();
  const int b = blockIdx.y;
  const int base = blockIdx.x * SCHUNK;
  const int B1 = g_binB1[b];
  const int lim = min(base + SCHUNK, NN);
  for (int n = base + threadIdx.x; n < lim; n += 256) {
    unsigned int mono = f2mono(g_scores[(size_t)b * NN + n]);
    if ((int)(mono >> 18) >= B1) {
      int p = atomicAdd(&lcnt, 1);
      if (p < CANDN)
        lbuf[p] = ((unsigned long long)(~mono) << 32) | (unsigned int)n;
    }
  }
  __syncthreads();
  if (threadIdx.x == 0) {
    int c = min(lcnt, CANDN);
    lbase = atomicAdd(&g_candCount[b], c);
    lcnt = c;
  }
  __syncthreads();
  const int c = lcnt, gb = lbase;
  for (int i = threadIdx.x; i < c; i += 256) {
    int pos = gb + i;
    if (pos < CANDN) g_cand[(size_t)b * CANDN + pos] = lbuf[i];
  }
}

// Kernel 4: per-batch bitonic sort; key = (~mono)<<32 | idx.
// ascending == (score desc, index asc) == lax.top_k order.
__global__ __launch_bounds__(1024) void k_sort() {
  __shared__ unsigned long long s[CANDN];
  const int b = blockIdx.x;
  const int cnt = min(g_candCount[b], CANDN);
  for (int i = threadIdx.x; i < CANDN; i += 1024)
    s[i] = (i < cnt) ? g_cand[(size_t)b * CANDN + i] : ~0ull;
  for (int k = 2; k <= CANDN; k <<= 1) {
    for (int j = k >> 1; j > 0; j >>= 1) {
      __syncthreads();
      for (int t = threadIdx.x; t < CANDN / 2; t += 1024) {
        int i = ((t / j) * 2 * j) + (t % j);
        int ij = i + j;
        unsigned long long a = s[i], c2 = s[ij];
        bool up = ((i & k) == 0);
        if ((a > c2) == up) { s[i] = c2; s[ij] = a; }
      }
    }
  }
  __syncthreads();
  for (int i = threadIdx.x; i < TOPK; i += 1024)
    g_topk[(size_t)b * TOPK + i] = (unsigned int)(s[i] & 0xffffffffu);
}

// Kernel 5: gather boxes; label/dir/score; standup boxes in f64.
__global__ void k_gather(const float* __restrict__ box, const float* __restrict__ cls,
                         const float* __restrict__ dirp) {
  const int b = blockIdx.y;
  const int k = blockIdx.x * 256 + threadIdx.x;
  if (k >= TOPK) return;
  const unsigned int n = g_topk[(size_t)b * TOPK + k];
  const float* bp = box + ((size_t)b * NN + n) * 7;
  float bx[7];
#pragma unroll
  for (int c = 0; c < 7; c++) {
    bx[c] = bp[c];
    g_tb_box[((size_t)b * TOPK + k) * 7 + c] = bx[c];
  }
  const float* cp = cls + ((size_t)b * NN + n) * CC;
  float best = cp[0]; int lab = 0;
#pragma unroll
  for (int c = 1; c < CC; c++) { float v = cp[c]; if (v > best) { best = v; lab = c; } }
  g_tb_score[(size_t)b * TOPK + k] = (float)(1.0 / (1.0 + exp(-(double)best)));
  g_tb_lab[(size_t)b * TOPK + k] = lab;
  const float* dp = dirp + ((size_t)b * NN + n) * 2;
  g_tb_dir[(size_t)b * TOPK + k] = (dp[1] > dp[0]) ? 1 : 0;

  const double cx = bx[0], cy = bx[1], w = bx[3], l = bx[4], ang = bx[6];
  const double c_ = cos(ang), s_ = sin(ang);
  const double hw = 0.5 * w, hl = 0.5 * l;
  double rx0 = (-hw) * c_ - (-hl) * s_ + cx;
  double rx1 = (-hw) * c_ - ( hl) * s_ + cx;
  double rx2 = ( hw) * c_ - ( hl) * s_ + cx;
  double rx3 = ( hw) * c_ - (-hl) * s_ + cx;
  double ry0 = (-hw) * s_ + (-hl) * c_ + cy;
  double ry1 = (-hw) * s_ + ( hl) * c_ + cy;
  double ry2 = ( hw) * s_ + ( hl) * c_ + cy;
  double ry3 = ( hw) * s_ + (-hl) * c_ + cy;
  double x1 = fmin(fmin(rx0, rx1), fmin(rx2, rx3));
  double y1 = fmin(fmin(ry0, ry1), fmin(ry2, ry3));
  double x2 = fmax(fmax(rx0, rx1), fmax(rx2, rx3));
  double y2 = fmax(fmax(ry0, ry1), fmax(ry2, ry3));
  double* sp = g_su + ((size_t)b * TOPK + k) * 4;
  sp[0] = x1; sp[1] = y1; sp[2] = x2; sp[3] = y2;
  g_area[(size_t)b * TOPK + k] = (x2 - x1) * (y2 - y1);
}

// Kernel 6: IoU suppression bitmask (f64).
__global__ void k_nms() {
  const int b = blockIdx.y, i = blockIdx.x;
  const double* sb = g_su + (size_t)b * TOPK * 4;
  const double ix1 = sb[(size_t)i * 4 + 0], iy1 = sb[(size_t)i * 4 + 1];
  const double ix2 = sb[(size_t)i * 4 + 2], iy2 = sb[(size_t)i * 4 + 3];
  const double ai = g_area[(size_t)b * TOPK + i];
  for (int it = 0; it < 4; it++) {
    const int j = it * 256 + threadIdx.x;
    bool pred = false;
    if (j < TOPK && j > i) {
      const double* q = sb + (size_t)j * 4;
      double ltx = fmax(ix1, q[0]), lty = fmax(iy1, q[1]);
      double rbx = fmin(ix2, q[2]), rby = fmin(iy2, q[3]);
      double w = fmax(rbx - ltx, 0.0), h = fmax(rby - lty, 0.0);
      double inter = w * h;
      double iou = inter / (ai + g_area[(size_t)b * TOPK + j] - inter + 1e-8);
      pred = iou > 0.1;
    }
    unsigned long long bal = __ballot(pred);
    if ((threadIdx.x & 63) == 0)
      g_mask[((size_t)b * TOPK + i) * 16 + (unsigned)(j >> 6)] = bal;
  }
}

// Kernel 7: greedy suppression scan, kept-row-proportional (1 wave/batch).
__global__ __launch_bounds__(64) void k_scan() {
  const int b = blockIdx.x;
  const int lane = threadIdx.x;
  const unsigned long long* mb = g_mask + (size_t)b * TOPK * 16;
  unsigned long long remv = 0ull;   // lane j<16: accumulated mask word j
  int cnt = 0;
  for (int g = 0; g < 16 && cnt < PROPN; g++) {
    unsigned long long cur = __shfl(remv, g);
    const int rmax = min(64, TOPK - g * 64);
    const unsigned long long vmask =
        (rmax >= 64) ? ~0ull : ((1ull << rmax) - 1ull);
    unsigned long long todo = ~cur & vmask;
    while (todo) {
      const int r = __ffsll((long long)todo) - 1;
      const int i = g * 64 + r;
      if (cnt < PROPN && lane == 0) g_outIdx[b * PROPN + cnt] = i;
      cnt++;
      if (cnt >= PROPN) break;
      unsigned long long mw = (lane < 16) ? mb[(size_t)i * 16 + lane] : 0ull;
      remv |= mw;
      cur |= __shfl(mw, g);
      const unsigned long long above = (r >= 63) ? 0ull : (~0ull << (r + 1));
      todo = ~cur & vmask & above;
    }
  }
  if (lane == 0) g_validCount[b] = cnt;
}

// Kernel 8: write FLOAT32 outputs: boxes | ids | scores.
__global__ void k_out(float* __restrict__ out, int seg) {
  const int b = blockIdx.x;
  const int r = threadIdx.x;
  if (r >= PROPN) return;
  const int K = g_validCount[b];
  float* boxo = out + ((size_t)b * PROPN + r) * 7;
  float* ido = out + (size_t)seg * 7 + (size_t)b * PROPN + r;
  float* sco = out + (size_t)seg * 8 + (size_t)b * PROPN + r;
  if (r < K) {
    const int i = g_outIdx[b * PROPN + r];
    const float* bx = g_tb_box + ((size_t)b * TOPK + i) * 7;
#pragma unroll
    for (int c = 0; c < 6; c++) boxo[c] = bx[c];
    const double period = 3.14159265358979323846;
    double ang = (double)bx[6];
    double rot = ang - floor(ang / period) * period;
    double na = rot + period * (double)g_tb_dir[(size_t)b * TOPK + i];
    boxo[6] = (float)na;
    *ido = (float)g_tb_lab[(size_t)b * TOPK + i];
    *sco = g_tb_score[(size_t)b * TOPK + i];
  } else {
#pragma unroll
    for (int c = 0; c < 7; c++) boxo[c] = 0.0f;
    *ido = 0.0f;
    *sco = 0.0f;
  }
}

extern "C" void kernel_launch(void* const* d_in, const int* in_sizes, int n_in,
                              void* d_out, int out_size, void* d_ws, size_t ws_size,
                              hipStream_t stream) {
  (void)d_ws; (void)ws_size;
  const float* box = nullptr;
  const float* cls = nullptr;
  const float* dirp = nullptr;
  for (int i = 0; i < n_in; i++) {
    long long s = in_sizes[i];
    if (s == (long long)BB * NN * 7) box = (const float*)d_in[i];
    else if (s == (long long)BB * NN * CC) cls = (const float*)d_in[i];
    else if (s == (long long)BB * NN * 2) dirp = (const float*)d_in[i];
  }
  const int seg = out_size / 9;  // = BB*PROPN = 1600

  k_init<<<(BB * NBINS + 255) / 256, 256, 0, stream>>>();
  k_score<<<dim3((NN + SCHUNK - 1) / SCHUNK, BB), 256, 0, stream>>>(cls);
  k_hist<<<dim3((NN + HCHUNK - 1) / HCHUNK, BB), 256, 0, stream>>>();
  k_pickbin<<<BB, 256, 0, stream>>>();
  k_compact<<<dim3((NN + SCHUNK - 1) / SCHUNK, BB), 256, 0, stream>>>();
  k_sort<<<BB, 1024, 0, stream>>>();
  k_gather<<<dim3(4, BB), 256, 0, stream>>>(box, cls, dirp);
  k_nms<<<dim3(TOPK, BB), 256, 0, stream>>>();
  k_scan<<<BB, 64, 0, stream>>>();
  k_out<<<BB, 256, 0, stream>>>((float*)d_out, seg);
}

// Round 8
// 106.712 us; speedup vs baseline: 2.4323x; 1.1996x over previous
//
#include <hip/hip_runtime.h>
#include <hip/hip_bf16.h>

#define BB 8
#define NN 200000
#define CC 10
#define NBINS 16384
#define TOPK 1000
#define CANDN 4096
#define PROPN 200

// ---- Static device scratch (no dependence on ws_size) ----
__device__ unsigned int g_hist[BB * NBINS];
__device__ int g_candCount[BB];
__device__ int g_binB1[BB];
__device__ float g_scores[(size_t)BB * NN];
__device__ unsigned long long g_cand[BB * CANDN];
__device__ unsigned int g_topk[BB * TOPK];
__device__ float g_tb_box[BB * TOPK * 7];
__device__ double g_su[BB * TOPK * 4];
__device__ double g_area[BB * TOPK];
__device__ float g_tb_score[BB * TOPK];
__device__ int g_tb_lab[BB * TOPK];
__device__ int g_tb_dir[BB * TOPK];
__device__ unsigned long long g_mask[BB * TOPK * 16];
__device__ int g_outIdx[BB * PROPN];
__device__ int g_validCount[BB];

__device__ __forceinline__ unsigned int f2mono(float f) {
  unsigned int u = __float_as_uint(f);
  return (u & 0x80000000u) ? ~u : (u | 0x80000000u);
}

// Kernel 0: zero histogram + candidate counters (idempotent per call).
__global__ void k_init() {
  const int i = blockIdx.x * 256 + threadIdx.x;
  if (i < BB * NBINS) g_hist[i] = 0u;
  if (i < BB) g_candCount[i] = 0;
}

// Kernel 1: pure streaming per-box max logit (10KB LDS -> high occupancy).
#define SCHUNK 2048
__global__ __launch_bounds__(256) void k_score(const float* __restrict__ cls) {
  __shared__ float sb[256 * CC];          // 10 KB staging
  const int b = blockIdx.y;
  const int base = blockIdx.x * SCHUNK;
  const float* cp = cls + ((size_t)b * NN + base) * CC;
  const int nbox = min(SCHUNK, NN - base);
  for (int c0 = 0; c0 < nbox; c0 += 256) {
    const int nb = min(256, nbox - c0);      // 256 or 64 (tail): nb*CC % 4 == 0
    const int nf4 = nb * CC / 4;
    const float4* src = (const float4*)(cp + (size_t)c0 * CC);
    for (int i = threadIdx.x; i < nf4; i += 256)
      ((float4*)sb)[i] = src[i];
    __syncthreads();
    if (threadIdx.x < nb) {
      const float2* p = (const float2*)(sb + threadIdx.x * CC);  // 8B-aligned
      float2 v0 = p[0], v1 = p[1], v2 = p[2], v3 = p[3], v4 = p[4];
      float m = fmaxf(fmaxf(fmaxf(v0.x, v0.y), fmaxf(v1.x, v1.y)),
                      fmaxf(fmaxf(v2.x, v2.y),
                            fmaxf(fmaxf(v3.x, v3.y), fmaxf(v4.x, v4.y))));
      g_scores[(size_t)b * NN + base + c0 + threadIdx.x] = m;
    }
    __syncthreads();
  }
}

// Kernel 1b: 14-bit-prefix histogram from g_scores (L2/L3-hot, 6.4 MB).
#define HCHUNK 4096
__global__ __launch_bounds__(256) void k_hist() {
  __shared__ unsigned int h[NBINS];       // 64 KB
  for (int i = threadIdx.x; i < NBINS; i += 256) h[i] = 0u;
  __syncthreads();
  const int b = blockIdx.y;
  const int base = blockIdx.x * HCHUNK;
  const int nv = min(HCHUNK, NN - base) / 4;   // all multiples of 4
  const float4* sp = (const float4*)(g_scores + (size_t)b * NN + base);
  for (int i = threadIdx.x; i < nv; i += 256) {
    float4 v = sp[i];
    atomicAdd(&h[f2mono(v.x) >> 18], 1u);
    atomicAdd(&h[f2mono(v.y) >> 18], 1u);
    atomicAdd(&h[f2mono(v.z) >> 18], 1u);
    atomicAdd(&h[f2mono(v.w) >> 18], 1u);
  }
  __syncthreads();
  unsigned int* hg = g_hist + (size_t)b * NBINS;
  for (int i = threadIdx.x; i < NBINS; i += 256)
    if (h[i]) atomicAdd(&hg[i], h[i]);
}

// Kernel 2: find threshold bin (scan from top until cumulative >= TOPK).
__global__ void k_pickbin() {
  const int b = blockIdx.x;
  __shared__ unsigned int csum[256];
  const unsigned int* h = g_hist + (size_t)b * NBINS;
  unsigned int s = 0;
  const int c0 = threadIdx.x * 64;
  for (int i = 0; i < 64; i++) s += h[c0 + i];
  csum[threadIdx.x] = s;
  __syncthreads();
  if (threadIdx.x == 0) {
    unsigned int cum = 0; int bin = 0; bool done = false;
    for (int cc = 255; cc >= 0 && !done; cc--) {
      if (cum + csum[cc] >= (unsigned)TOPK) {
        for (int i = 63; i >= 0; i--) {
          unsigned int v = h[cc * 64 + i];
          if (cum + v >= (unsigned)TOPK) { bin = cc * 64 + i; done = true; break; }
          cum += v;
        }
      } else {
        cum += csum[cc];
      }
    }
    g_binB1[b] = bin;
  }
}

// Kernel 3: compact candidates. Per-block LDS buffer + ONE global atomic/block.
__global__ __launch_bounds__(256) void k_compact() {
  __shared__ unsigned long long lbuf[CANDN];   // 32 KB
  __shared__ int lcnt, lbase;
  if (threadIdx.x == 0) lcnt = 0;
  __syncthreads();
  const int b = blockIdx.y;
  const int base = blockIdx.x * SCHUNK;
  const int B1 = g_binB1[b];
  const int lim = min(base + SCHUNK, NN);
  for (int n = base + threadIdx.x; n < lim; n += 256) {
    unsigned int mono = f2mono(g_scores[(size_t)b * NN + n]);
    if ((int)(mono >> 18) >= B1) {
      int p = atomicAdd(&lcnt, 1);
      if (p < CANDN)
        lbuf[p] = ((unsigned long long)(~mono) << 32) | (unsigned int)n;
    }
  }
  __syncthreads();
  if (threadIdx.x == 0) {
    int c = min(lcnt, CANDN);
    lbase = atomicAdd(&g_candCount[b], c);
    lcnt = c;
  }
  __syncthreads();
  const int c = lcnt, gb = lbase;
  for (int i = threadIdx.x; i < c; i += 256) {
    int pos = gb + i;
    if (pos < CANDN) g_cand[(size_t)b * CANDN + pos] = lbuf[i];
  }
}

// Kernel 4: all-pairs RANK select (replaces bitonic sort).
// rank(x) = #{keys < x}; keys unique (idx in low bits) -> exact permutation.
// rank < TOPK  =>  g_topk[rank] = idx. Reproduces (score desc, idx asc).
__global__ __launch_bounds__(256) void k_rank() {
  __shared__ unsigned long long tile[256];   // 2 KB
  const int b = blockIdx.y;
  const int cnt = min(g_candCount[b], CANDN);
  const int base = blockIdx.x * 256;
  if (base >= cnt) return;
  const int me = base + threadIdx.x;
  const bool valid = me < cnt;
  const unsigned long long mykey =
      valid ? g_cand[(size_t)b * CANDN + me] : ~0ull;
  int rank = 0;
  for (int t0 = 0; t0 < cnt; t0 += 256) {
    const int tn = min(256, cnt - t0);
    __syncthreads();
    if (threadIdx.x < tn)
      tile[threadIdx.x] = g_cand[(size_t)b * CANDN + t0 + threadIdx.x];
    __syncthreads();
    for (int j = 0; j < tn; j++)            // broadcast LDS read per iter
      rank += (tile[j] < mykey) ? 1 : 0;
  }
  if (valid && rank < TOPK)
    g_topk[(size_t)b * TOPK + rank] = (unsigned int)(mykey & 0xffffffffu);
}

// Kernel 5: gather boxes; label/dir/score; standup boxes in f64.
__global__ void k_gather(const float* __restrict__ box, const float* __restrict__ cls,
                         const float* __restrict__ dirp) {
  const int b = blockIdx.y;
  const int k = blockIdx.x * 256 + threadIdx.x;
  if (k >= TOPK) return;
  const unsigned int n = g_topk[(size_t)b * TOPK + k];
  const float* bp = box + ((size_t)b * NN + n) * 7;
  float bx[7];
#pragma unroll
  for (int c = 0; c < 7; c++) {
    bx[c] = bp[c];
    g_tb_box[((size_t)b * TOPK + k) * 7 + c] = bx[c];
  }
  const float* cp = cls + ((size_t)b * NN + n) * CC;
  float best = cp[0]; int lab = 0;
#pragma unroll
  for (int c = 1; c < CC; c++) { float v = cp[c]; if (v > best) { best = v; lab = c; } }
  g_tb_score[(size_t)b * TOPK + k] = (float)(1.0 / (1.0 + exp(-(double)best)));
  g_tb_lab[(size_t)b * TOPK + k] = lab;
  const float* dp = dirp + ((size_t)b * NN + n) * 2;
  g_tb_dir[(size_t)b * TOPK + k] = (dp[1] > dp[0]) ? 1 : 0;

  const double cx = bx[0], cy = bx[1], w = bx[3], l = bx[4], ang = bx[6];
  const double c_ = cos(ang), s_ = sin(ang);
  const double hw = 0.5 * w, hl = 0.5 * l;
  double rx0 = (-hw) * c_ - (-hl) * s_ + cx;
  double rx1 = (-hw) * c_ - ( hl) * s_ + cx;
  double rx2 = ( hw) * c_ - ( hl) * s_ + cx;
  double rx3 = ( hw) * c_ - (-hl) * s_ + cx;
  double ry0 = (-hw) * s_ + (-hl) * c_ + cy;
  double ry1 = (-hw) * s_ + ( hl) * c_ + cy;
  double ry2 = ( hw) * s_ + ( hl) * c_ + cy;
  double ry3 = ( hw) * s_ + (-hl) * c_ + cy;
  double x1 = fmin(fmin(rx0, rx1), fmin(rx2, rx3));
  double y1 = fmin(fmin(ry0, ry1), fmin(ry2, ry3));
  double x2 = fmax(fmax(rx0, rx1), fmax(rx2, rx3));
  double y2 = fmax(fmax(ry0, ry1), fmax(ry2, ry3));
  double* sp = g_su + ((size_t)b * TOPK + k) * 4;
  sp[0] = x1; sp[1] = y1; sp[2] = x2; sp[3] = y2;
  g_area[(size_t)b * TOPK + k] = (x2 - x1) * (y2 - y1);
}

// Kernel 6: IoU suppression bitmask (f64).
__global__ void k_nms() {
  const int b = blockIdx.y, i = blockIdx.x;
  const double* sb = g_su + (size_t)b * TOPK * 4;
  const double ix1 = sb[(size_t)i * 4 + 0], iy1 = sb[(size_t)i * 4 + 1];
  const double ix2 = sb[(size_t)i * 4 + 2], iy2 = sb[(size_t)i * 4 + 3];
  const double ai = g_area[(size_t)b * TOPK + i];
  for (int it = 0; it < 4; it++) {
    const int j = it * 256 + threadIdx.x;
    bool pred = false;
    if (j < TOPK && j > i) {
      const double* q = sb + (size_t)j * 4;
      double ltx = fmax(ix1, q[0]), lty = fmax(iy1, q[1]);
      double rbx = fmin(ix2, q[2]), rby = fmin(iy2, q[3]);
      double w = fmax(rbx - ltx, 0.0), h = fmax(rby - lty, 0.0);
      double inter = w * h;
      double iou = inter / (ai + g_area[(size_t)b * TOPK + j] - inter + 1e-8);
      pred = iou > 0.1;
    }
    unsigned long long bal = __ballot(pred);
    if ((threadIdx.x & 63) == 0)
      g_mask[((size_t)b * TOPK + i) * 16 + (unsigned)(j >> 6)] = bal;
  }
}

// Kernel 7: greedy suppression scan, kept-row-proportional (1 wave/batch).
__global__ __launch_bounds__(64) void k_scan() {
  const int b = blockIdx.x;
  const int lane = threadIdx.x;
  const unsigned long long* mb = g_mask + (size_t)b * TOPK * 16;
  unsigned long long remv = 0ull;   // lane j<16: accumulated mask word j
  int cnt = 0;
  for (int g = 0; g < 16 && cnt < PROPN; g++) {
    unsigned long long cur = __shfl(remv, g);
    const int rmax = min(64, TOPK - g * 64);
    const unsigned long long vmask =
        (rmax >= 64) ? ~0ull : ((1ull << rmax) - 1ull);
    unsigned long long todo = ~cur & vmask;
    while (todo) {
      const int r = __ffsll((long long)todo) - 1;
      const int i = g * 64 + r;
      if (cnt < PROPN && lane == 0) g_outIdx[b * PROPN + cnt] = i;
      cnt++;
      if (cnt >= PROPN) break;
      unsigned long long mw = (lane < 16) ? mb[(size_t)i * 16 + lane] : 0ull;
      remv |= mw;
      cur |= __shfl(mw, g);
      const unsigned long long above = (r >= 63) ? 0ull : (~0ull << (r + 1));
      todo = ~cur & vmask & above;
    }
  }
  if (lane == 0) g_validCount[b] = cnt;
}

// Kernel 8: write FLOAT32 outputs: boxes | ids | scores.
__global__ void k_out(float* __restrict__ out, int seg) {
  const int b = blockIdx.x;
  const int r = threadIdx.x;
  if (r >= PROPN) return;
  const int K = g_validCount[b];
  float* boxo = out + ((size_t)b * PROPN + r) * 7;
  float* ido = out + (size_t)seg * 7 + (size_t)b * PROPN + r;
  float* sco = out + (size_t)seg * 8 + (size_t)b * PROPN + r;
  if (r < K) {
    const int i = g_outIdx[b * PROPN + r];
    const float* bx = g_tb_box + ((size_t)b * TOPK + i) * 7;
#pragma unroll
    for (int c = 0; c < 6; c++) boxo[c] = bx[c];
    const double period = 3.14159265358979323846;
    double ang = (double)bx[6];
    double rot = ang - floor(ang / period) * period;
    double na = rot + period * (double)g_tb_dir[(size_t)b * TOPK + i];
    boxo[6] = (float)na;
    *ido = (float)g_tb_lab[(size_t)b * TOPK + i];
    *sco = g_tb_score[(size_t)b * TOPK + i];
  } else {
#pragma unroll
    for (int c = 0; c < 7; c++) boxo[c] = 0.0f;
    *ido = 0.0f;
    *sco = 0.0f;
  }
}

extern "C" void kernel_launch(void* const* d_in, const int* in_sizes, int n_in,
                              void* d_out, int out_size, void* d_ws, size_t ws_size,
                              hipStream_t stream) {
  (void)d_ws; (void)ws_size;
  const float* box = nullptr;
  const float* cls = nullptr;
  const float* dirp = nullptr;
  for (int i = 0; i < n_in; i++) {
    long long s = in_sizes[i];
    if (s == (long long)BB * NN * 7) box = (const float*)d_in[i];
    else if (s == (long long)BB * NN * CC) cls = (const float*)d_in[i];
    else if (s == (long long)BB * NN * 2) dirp = (const float*)d_in[i];
  }
  const int seg = out_size / 9;  // = BB*PROPN = 1600

  k_init<<<(BB * NBINS + 255) / 256, 256, 0, stream>>>();
  k_score<<<dim3((NN + SCHUNK - 1) / SCHUNK, BB), 256, 0, stream>>>(cls);
  k_hist<<<dim3((NN + HCHUNK - 1) / HCHUNK, BB), 256, 0, stream>>>();
  k_pickbin<<<BB, 256, 0, stream>>>();
  k_compact<<<dim3((NN + SCHUNK - 1) / SCHUNK, BB), 256, 0, stream>>>();
  k_rank<<<dim3(CANDN / 256, BB), 256, 0, stream>>>();
  k_gather<<<dim3(4, BB), 256, 0, stream>>>(box, cls, dirp);
  k_nms<<<dim3(TOPK, BB), 256, 0, stream>>>();
  k_scan<<<BB, 64, 0, stream>>>();
  k_out<<<BB, 256, 0, stream>>>((float*)d_out, seg);
}